// Round 6
// baseline (722.650 us; speedup 1.0000x reference)
//
#include <hip/hip_runtime.h>
#include <math.h>

#define BB   16
#define NN   32768
#define GG   128
#define KK   64
#define EDD  384
#define NT1  1024
#define PPT  32   // NN / NT1 (k_grp topk phase)
#define PT   32   // points per thread in k_fps (NN / NT1)
#define FJ   12   // LDS-resident point slots per thread (static, 144 KB)
#define RJ   20   // AGPR-resident point slots per thread (FJ + RJ = PT)

// ---- workspace layout (float offsets) ----
#define WS_GC     0          // [16][2][3]      = 96     (c0, cm per batch)
#define WS_F2     6240       // [32][256][64]   = 524288
#define WS_FG     530528     // [32][256]       = 8192
#define WS_F4     538720     // [32][512][64]   = 1048576

__device__ __forceinline__ float sq3(float a, float b, float c) {
  // matches np: ((a*a + b*b) + c*c), no FMA contraction
  return __fadd_rn(__fadd_rn(__fmul_rn(a, a), __fmul_rn(b, b)), __fmul_rn(c, c));
}
__device__ __forceinline__ float dot3(float ax, float ay, float az,
                                      float bx, float by, float bz) {
  return __fadd_rn(__fadd_rn(__fmul_rn(ax, bx), __fmul_rn(ay, by)), __fmul_rn(az, bz));
}
__device__ __forceinline__ unsigned long long shfl_xor_u64(unsigned long long v,
                                                           int off) {
  unsigned lo = (unsigned)v, hi = (unsigned)(v >> 32);
  lo = __shfl_xor(lo, off);
  hi = __shfl_xor(hi, off);
  return ((unsigned long long)hi << 32) | lo;
}

// ---------------------------------------------------------------------------
// Kernel 1: FPS. ONE block per batch (16 blocks x 1024 threads) -> zero
// cross-block sync. Residency (32 pts/thread):
//   dist[32] + working set  -> arch VGPRs (~50, fits the 64-arch half)
//   20 coord-triples (60)   -> AGPRs, EXPLICIT v_accvgpr_write/read asm
//   12 coord-triples        -> static LDS (144 KB, thread-owned slots)
// R5 post-mortem: 1024-thread block caps total regs at 128/thread; the
// compiler split 64 arch + 64 acc and shuffled coords through AGPRs its own
// way (~1.6x instr stream, 3.1 us/round). This version makes the split
// explicit and minimal: exactly one v_accvgpr_read per coord per round
// (60 reads, ~+7%), arch pressure genuinely <= 64 so nothing is
// rematerialized or juggled. Reads are asm volatile INSIDE the loop so they
// cannot be hoisted into 60 live VGPRs.
// Per round: VALU update -> per-thread (bd,bj) -> wave butterfly on packed
// u64 (d_bits<<32 | ~idx : u64-max == np.argmax first-max rule) -> lane0
// writes redp[parity][wave] -> ONE __syncthreads -> every lane reads
// redp[parity][lane&15] + 4-step butterfly -> all lanes hold winner; coords
// re-read from P via scalar broadcast. Parity double-buffer makes the single
// barrier race-free.
// ---------------------------------------------------------------------------
__global__ void __launch_bounds__(NT1)
k_fps(const float* __restrict__ points, float* __restrict__ out,
      float* __restrict__ ws) {
  __shared__ float2 xyL[FJ * NT1];           // 96 KB  (static => known size)
  __shared__ float  zL[FJ * NT1];            // 48 KB
  __shared__ float cent[GG * 3];
  __shared__ float darr[GG];
  __shared__ int msh[1];
  __shared__ unsigned long long redp[2][16];

  const int b    = blockIdx.x;
  const int t    = threadIdx.x;
  const int wave = t >> 6, lane = t & 63;
  const float* P = points + (size_t)b * NN * 3;

  // stage: j in [0,FJ) -> LDS (thread-owned slots)
#pragma unroll
  for (int j = 0; j < FJ; ++j) {
    const float* pp = P + (size_t)(t + j * NT1) * 3;
    xyL[j * NT1 + t] = make_float2(pp[0], pp[1]);
    zL[j * NT1 + t]  = pp[2];
  }
  // stage: j in [FJ,PT) -> AGPRs (explicit park; "a" = AGPR constraint)
  float agx[RJ], agy[RJ], agz[RJ];
#pragma unroll
  for (int r = 0; r < RJ; ++r) {
    const float* pp = P + (size_t)(t + (FJ + r) * NT1) * 3;
    float x = pp[0], y = pp[1], z = pp[2];
    asm volatile("v_accvgpr_write_b32 %0, %1" : "=a"(agx[r]) : "v"(x));
    asm volatile("v_accvgpr_write_b32 %0, %1" : "=a"(agy[r]) : "v"(y));
    asm volatile("v_accvgpr_write_b32 %0, %1" : "=a"(agz[r]) : "v"(z));
  }
  float dist[PT];
#pragma unroll
  for (int j = 0; j < PT; ++j) dist[j] = INFINITY;

  float cx = P[0], cy = P[1], cz = P[2];  // centroid 0 = point 0
  if (t == 0) { cent[0] = cx; cent[1] = cy; cent[2] = cz; }

  for (int it = 1; it < GG; ++it) {
    float bd = -INFINITY; int bj = 0;
    // AGPR-resident points: one accvgpr_read per coord per round (volatile
    // => not hoistable => never 60 live arch VGPRs)
#pragma unroll
    for (int r = 0; r < RJ; ++r) {
      const int j = FJ + r;
      float x, y, z;
      asm volatile("v_accvgpr_read_b32 %0, %1" : "=v"(x) : "a"(agx[r]));
      asm volatile("v_accvgpr_read_b32 %0, %1" : "=v"(y) : "a"(agy[r]));
      asm volatile("v_accvgpr_read_b32 %0, %1" : "=v"(z) : "a"(agz[r]));
      float dx = __fsub_rn(x, cx);
      float dy = __fsub_rn(y, cy);
      float dz = __fsub_rn(z, cz);
      float d  = __fadd_rn(__fadd_rn(__fmul_rn(dx, dx), __fmul_rn(dy, dy)),
                           __fmul_rn(dz, dz));
      float nd = fminf(dist[j], d);
      dist[j] = nd;
      if (nd > bd) { bd = nd; bj = j; }  // ascending j + strict > => first-max
    }
    // LDS-resident points (thread-owned slots; ds_read with imm offsets)
#pragma unroll
    for (int j = 0; j < FJ; ++j) {
      float2 xy = xyL[j * NT1 + t];
      float  zz = zL[j * NT1 + t];
      float dx = __fsub_rn(xy.x, cx);
      float dy = __fsub_rn(xy.y, cy);
      float dz = __fsub_rn(zz, cz);
      float d  = __fadd_rn(__fadd_rn(__fmul_rn(dx, dx), __fmul_rn(dy, dy)),
                           __fmul_rn(dz, dz));
      float nd = fminf(dist[j], d);
      dist[j] = nd;
      if (nd > bd) { bd = nd; bj = j; }
    }
    // point j of thread t has global index t + j*NT1; bj ascending in global
    // index => within-thread first-max; cross-thread via ~idx in packed key.
    unsigned long long bp =
        ((unsigned long long)__float_as_uint(bd) << 32) |
        (unsigned)~(unsigned)(t + (bj << 10));
#pragma unroll
    for (int off = 1; off < 64; off <<= 1) {
      unsigned long long o = shfl_xor_u64(bp, off);
      if (o > bp) bp = o;
    }
    if (lane == 0) redp[it & 1][wave] = bp;
    __syncthreads();  // the ONLY barrier per round
    unsigned long long v = redp[it & 1][lane & 15];
#pragma unroll
    for (int off = 1; off < 16; off <<= 1) {
      unsigned long long o = shfl_xor_u64(v, off);
      if (o > v) v = o;
    }
    int sv = __builtin_amdgcn_readfirstlane((int)~(unsigned)v);
    const float* wp = P + (size_t)sv * 3;  // scalar broadcast load
    cx = wp[0]; cy = wp[1]; cz = wp[2];
    if (t == 0) {
      cent[it * 3 + 0] = cx; cent[it * 3 + 1] = cy; cent[it * 3 + 2] = cz;
    }
  }
  __syncthreads();  // cent[] complete, visible to all

  // morton step 1: m = argmin_{j>=1} cdist(c0, cj), ref expansion formula
  if (t < GG) {
    float c0x = cent[0], c0y = cent[1], c0z = cent[2];
    float cjx = cent[t * 3 + 0], cjy = cent[t * 3 + 1], cjz = cent[t * 3 + 2];
    float sa = sq3(c0x, c0y, c0z);
    float sb = sq3(cjx, cjy, cjz);
    float dt = dot3(c0x, c0y, c0z, cjx, cjy, cjz);
    float dd = __fsub_rn(__fadd_rn(sa, sb), __fmul_rn(2.0f, dt));
    darr[t] = (t == 0) ? INFINITY : dd;
  }
  __syncthreads();
  if (t == 0) {
    float vd = darr[1]; int vi = 1;
    for (int j = 2; j < GG; ++j) {
      float od = darr[j];
      if (od < vd) { vd = od; vi = j; }  // strict < => first-min
    }
    msh[0] = vi;
    float* gc = ws + WS_GC + b * 6;
    gc[0] = cent[0];          gc[1] = cent[1];          gc[2] = cent[2];
    gc[3] = cent[vi * 3 + 0]; gc[4] = cent[vi * 3 + 1]; gc[5] = cent[vi * 3 + 2];
  }
  __syncthreads();
  int m = msh[0];
  // centroid output: pos0 = c0, pos1 = cm, pos>=2 = c0 (morton degeneracy)
  if (t < GG * 3) {
    int pos = t / 3, c = t % 3;
    float v = (pos == 1) ? cent[m * 3 + c] : cent[c];
    out[(size_t)b * GG * 3 + t] = v;
  }
}

// ---------------------------------------------------------------------------
// Kernel 2 (fused topk + encA): per group (32 blocks x 1024 threads):
// top-64 extraction into LDS xl, then f1 = relu(bn1(w1@x+b1)),
// f2 = w2@f1 + b2 -> global, fg = max_k f2 -> global.
// f1s overlays the dead darr region after a barrier.
// ---------------------------------------------------------------------------
__global__ void __launch_bounds__(NT1) k_grp(
    const float* __restrict__ points, float* __restrict__ ws,
    const float* __restrict__ w1, const float* __restrict__ b1,
    const float* __restrict__ g1, const float* __restrict__ be1,
    const float* __restrict__ m1, const float* __restrict__ v1,
    const float* __restrict__ w2, const float* __restrict__ b2) {
  extern __shared__ float smem[];
  float* darr = smem;                        // [NN] (topk) / f1s overlay (encA)
  float* f1s  = smem;                        // [128*65] = 8320 <= NN
  float* redd = smem + NN;                   // [2][16]
  int*   redi = (int*)(smem + NN + 32);      // [2][16]
  float* xl   = smem + NN + 64;              // [KK*3]

  const int g = blockIdx.x;
  const int b = g >> 1, which = g & 1;
  const int t = threadIdx.x;
  const float* P = points + (size_t)b * NN * 3;
  const float* gc = ws + WS_GC + b * 6 + which * 3;
  const float cx = gc[0], cy = gc[1], cz = gc[2];
  const float sa = sq3(cx, cy, cz);

  // ---- phase 1: top-64 extraction ----
  float bd = INFINITY; int bg = 0;
#pragma unroll
  for (int j = 0; j < PPT; ++j) {
    int p = t + j * NT1;
    const float* pp = P + (size_t)p * 3;
    float px = pp[0], py = pp[1], pz = pp[2];
    float sb = sq3(px, py, pz);
    float dt = dot3(cx, cy, cz, px, py, pz);
    float d  = __fsub_rn(__fadd_rn(sa, sb), __fmul_rn(2.0f, dt));
    darr[p] = d;
    if (d < bd) { bd = d; bg = p; }  // ascending p + strict < => first-min
  }
  int my_win = 0;
  for (int r = 0; r < KK; ++r) {
    float rd = bd; int ri = bg;
#pragma unroll
    for (int off = 1; off < 64; off <<= 1) {
      float od = __shfl_xor(rd, off);
      int   oi = __shfl_xor(ri, off);
      if (od < rd || (od == rd && oi < ri)) { rd = od; ri = oi; }
    }
    const int par = (r & 1) * 16;
    if ((t & 63) == 0) { redd[par + (t >> 6)] = rd; redi[par + (t >> 6)] = ri; }
    __syncthreads();
    int l = t & 15;
    float vd = redd[par + l]; int vi = redi[par + l];
#pragma unroll
    for (int off = 1; off < 16; off <<= 1) {
      float od = __shfl_xor(vd, off);
      int   oi = __shfl_xor(vi, off);
      if (od < vd || (od == vd && oi < vi)) { vd = od; vi = oi; }
    }
    if (t == r) my_win = vi;
    if (t == (vi & (NT1 - 1))) {  // owner invalidates + rescans its 32 slots
      darr[vi] = INFINITY;
      bd = INFINITY; bg = 0;
#pragma unroll
      for (int j = 0; j < PPT; ++j) {
        int p = t + j * NT1;
        float v = darr[p];
        if (v < bd) { bd = v; bg = p; }
      }
    }
  }
  __syncthreads();  // darr dead after this point
  if (t < KK) {     // thread t holds round-t winner; local coords into LDS
    const float* pp = P + (size_t)my_win * 3;
    xl[t * 3 + 0] = __fsub_rn(pp[0], cx);
    xl[t * 3 + 1] = __fsub_rn(pp[1], cy);
    xl[t * 3 + 2] = __fsub_rn(pp[2], cz);
  }
  __syncthreads();

  // ---- phase 2: f1 = relu(bn1(w1@x + b1)) -> f1s[128][65] ----
  {
    const int o = t & 127, kh = t >> 7;  // kh in [0,8)
    float wx = w1[o * 3 + 0], wy = w1[o * 3 + 1], wz = w1[o * 3 + 2];
    float inv = g1[o] * (1.0f / sqrtf(v1[o] + 1e-5f));
    float add = be1[o] - m1[o] * inv;
    float bb = b1[o];
#pragma unroll
    for (int kk = 0; kk < 8; ++kk) {
      int k = kh * 8 + kk;
      float f = fmaf(wx, xl[k * 3 + 0],
                fmaf(wy, xl[k * 3 + 1],
                fmaf(wz, xl[k * 3 + 2], bb)));
      f = fmaf(f, inv, add);
      f1s[o * 65 + k] = fmaxf(f, 0.0f);
    }
  }
  __syncthreads();

  // ---- phase 3: f2 = w2@f1 + b2 -> global; fg = max_k -> global ----
  const int k  = t & 63;
  const int og = __builtin_amdgcn_readfirstlane(t >> 6);  // wave-uniform [0,16)
  const int o0 = og * 16;
  float acc[16];
#pragma unroll
  for (int oo = 0; oo < 16; ++oo) acc[oo] = b2[o0 + oo];
  for (int i = 0; i < 128; ++i) {
    float xv = f1s[i * 65 + k];
#pragma unroll
    for (int oo = 0; oo < 16; ++oo)
      acc[oo] = fmaf(w2[(o0 + oo) * 128 + i], xv, acc[oo]);  // uniform -> s_load
  }
  float* f2g = ws + WS_F2 + (size_t)g * 256 * 64;
  float* fgg = ws + WS_FG + g * 256;
#pragma unroll
  for (int oo = 0; oo < 16; ++oo) f2g[(o0 + oo) * 64 + k] = acc[oo];
#pragma unroll
  for (int oo = 0; oo < 16; ++oo) {
    float v = acc[oo];
#pragma unroll
    for (int off = 1; off < 64; off <<= 1) v = fmaxf(v, __shfl_xor(v, off));
    if (k == 0) fgg[o0 + oo] = v;
  }
}

// ---------------------------------------------------------------------------
// Kernel 3 (stage B): f4 = relu(bn2(w3 @ concat([fg bcast, f2]) + b3))
// grid = 32 groups x 16 o-chunks of 32 (512 blocks -> 2 blocks/CU -> 2
// waves/SIMD).
// ---------------------------------------------------------------------------
__global__ void __launch_bounds__(256) k_encB(
    float* __restrict__ ws,
    const float* __restrict__ w3, const float* __restrict__ b3,
    const float* __restrict__ g2, const float* __restrict__ be2,
    const float* __restrict__ m2, const float* __restrict__ v2) {
  __shared__ float part[32][8];
  __shared__ float sfg[32];
  const int blk = blockIdx.x;
  const int g = blk >> 4, oc = blk & 15;
  const int t = threadIdx.x;
  const int k = t & 63;
  const int og = __builtin_amdgcn_readfirstlane(t >> 6);  // [0,4)
  const int ob = oc * 32;
  const float* fgg = ws + WS_FG + g * 256;
  {  // k-independent part: sum_{i<256} w3[o][i] * fg[i]; o = t>>3, ih = t&7
    int o = t >> 3, ih = t & 7;
    float s = 0.0f;
    int i0 = ih * 32;
    for (int ii = 0; ii < 32; ++ii) {
      int i = i0 + ii;
      s = fmaf(w3[(size_t)(ob + o) * 512 + i], fgg[i], s);
    }
    part[o][ih] = s;
  }
  __syncthreads();
  if (t < 32) {
    float s = ((part[t][0] + part[t][1]) + (part[t][2] + part[t][3])) +
              ((part[t][4] + part[t][5]) + (part[t][6] + part[t][7]));
    sfg[t] = b3[ob + t] + s;
  }
  __syncthreads();
  const int o0 = ob + og * 8;
  float acc[8];
#pragma unroll
  for (int oo = 0; oo < 8; ++oo) acc[oo] = sfg[og * 8 + oo];
  const float* f2g = ws + WS_F2 + (size_t)g * 256 * 64;
#pragma unroll 4
  for (int i = 0; i < 256; ++i) {
    float xv = f2g[i * 64 + k];
#pragma unroll
    for (int oo = 0; oo < 8; ++oo)
      acc[oo] = fmaf(w3[(size_t)(o0 + oo) * 512 + 256 + i], xv, acc[oo]);
  }
  float* f4g = ws + WS_F4 + (size_t)g * 512 * 64;
#pragma unroll
  for (int oo = 0; oo < 8; ++oo) {
    int o = o0 + oo;
    float inv = g2[o] * (1.0f / sqrtf(v2[o] + 1e-5f));
    float add = be2[o] - m2[o] * inv;
    f4g[o * 64 + k] = fmaxf(fmaf(acc[oo], inv, add), 0.0f);
  }
}

// ---------------------------------------------------------------------------
// Kernel 4 (fused stage C + broadcast): token = max_k (w4 @ f4 + b4), written
// directly to all output positions (xor butterfly leaves max in ALL lanes;
// lanes scatter positions). grid = 32 x 24 chunks of 16 (768 blocks -> 2
// blocks/CU -> 2 waves/SIMD).
// ---------------------------------------------------------------------------
__global__ void __launch_bounds__(256) k_encCb(float* __restrict__ ws,
                                               const float* __restrict__ w4,
                                               const float* __restrict__ b4,
                                               float* __restrict__ out) {
  const int blk = blockIdx.x;
  const int g = blk / 24, oc = blk % 24;
  const int b = g >> 1, which = g & 1;
  const int t = threadIdx.x;
  const int k = t & 63;
  const int og = __builtin_amdgcn_readfirstlane(t >> 6);
  const int o0 = oc * 16 + og * 4;
  float acc[4];
#pragma unroll
  for (int oo = 0; oo < 4; ++oo) acc[oo] = b4[o0 + oo];
  const float* f4g = ws + WS_F4 + (size_t)g * 512 * 64;
#pragma unroll 8
  for (int i = 0; i < 512; ++i) {
    float xv = f4g[i * 64 + k];
#pragma unroll
    for (int oo = 0; oo < 4; ++oo)
      acc[oo] = fmaf(w4[(size_t)(o0 + oo) * 512 + i], xv, acc[oo]);
  }
#pragma unroll
  for (int oo = 0; oo < 4; ++oo) {
#pragma unroll
    for (int off = 1; off < 64; off <<= 1)
      acc[oo] = fmaxf(acc[oo], __shfl_xor(acc[oo], off));
  }
  // all lanes now hold the per-oo max; scatter to output positions
  float* tok = out + (size_t)BB * GG * 3;
  if (which == 1) {
    if (k == 0) {
      float* dst = tok + ((size_t)b * GG + 1) * EDD + o0;
#pragma unroll
      for (int oo = 0; oo < 4; ++oo) dst[oo] = acc[oo];
    }
  } else {
#pragma unroll
    for (int rep = 0; rep < 2; ++rep) {
      int pos = k + rep * 64;
      if (pos == 1) continue;
      float* dst = tok + ((size_t)b * GG + pos) * EDD + o0;
#pragma unroll
      for (int oo = 0; oo < 4; ++oo) dst[oo] = acc[oo];
    }
  }
}

extern "C" void kernel_launch(void* const* d_in, const int* in_sizes, int n_in,
                              void* d_out, int out_size, void* d_ws, size_t ws_size,
                              hipStream_t stream) {
  const float* points = (const float*)d_in[0];
  const float* w1  = (const float*)d_in[1];
  const float* b1  = (const float*)d_in[2];
  const float* g1  = (const float*)d_in[3];
  const float* be1 = (const float*)d_in[4];
  const float* m1  = (const float*)d_in[5];
  const float* v1  = (const float*)d_in[6];
  const float* w2  = (const float*)d_in[7];
  const float* b2  = (const float*)d_in[8];
  const float* w3  = (const float*)d_in[9];
  const float* b3  = (const float*)d_in[10];
  const float* g2  = (const float*)d_in[11];
  const float* be2 = (const float*)d_in[12];
  const float* m2  = (const float*)d_in[13];
  const float* v2  = (const float*)d_in[14];
  const float* w4  = (const float*)d_in[15];
  const float* b4  = (const float*)d_in[16];
  float* out = (float*)d_out;
  float* ws  = (float*)d_ws;

  // k_fps uses STATIC LDS (no dynamic attr needed). k_grp still dynamic.
  size_t dyn_grp = (size_t)(NN + 64 + KK * 3 + 16) * sizeof(float);
  hipFuncSetAttribute(reinterpret_cast<const void*>(k_grp),
                      hipFuncAttributeMaxDynamicSharedMemorySize, (int)dyn_grp);

  hipLaunchKernelGGL(k_fps, dim3(BB), dim3(NT1), 0, stream,
                     points, out, ws);
  hipLaunchKernelGGL(k_grp, dim3(32), dim3(NT1), dyn_grp, stream,
                     points, ws, w1, b1, g1, be1, m1, v1, w2, b2);
  hipLaunchKernelGGL(k_encB, dim3(512), dim3(256), 0, stream,
                     ws, w3, b3, g2, be2, m2, v2);
  hipLaunchKernelGGL(k_encCb, dim3(768), dim3(256), 0, stream, ws, w4, b4, out);
}

// Round 8
// 566.000 us; speedup vs baseline: 1.2768x; 1.2768x over previous
//
#include <hip/hip_runtime.h>
#include <math.h>

#define BB   16
#define NN   32768
#define GG   128
#define KK   64
#define EDD  384
#define NT1  1024
#define PPT  32   // NN / NT1 (k_grp topk phase)
#define SB   4    // k_fps blocks per batch
#define SP   (NN / SB)   // 8192 points per k_fps block
#define JP   (SP / NT1)  // 8 points/thread

// ---- workspace layout (float offsets) ----
#define WS_GC     0          // [16][2][3]      = 96     (c0, cm per batch)
#define WS_F2     6240       // [32][256][64]   = 524288
#define WS_FG     530528     // [32][256]       = 8192
#define WS_F4     538720     // [32][512][64]   = 1048576
#define WS_SYNC   1587296    // u64 [2 parity][16 batch][4 blk] = 1 KB

__device__ __forceinline__ float sq3(float a, float b, float c) {
  // matches np: ((a*a + b*b) + c*c), no FMA contraction
  return __fadd_rn(__fadd_rn(__fmul_rn(a, a), __fmul_rn(b, b)), __fmul_rn(c, c));
}
__device__ __forceinline__ float dot3(float ax, float ay, float az,
                                      float bx, float by, float bz) {
  return __fadd_rn(__fadd_rn(__fmul_rn(ax, bx), __fmul_rn(ay, by)), __fmul_rn(az, bz));
}
__device__ __forceinline__ unsigned long long shfl_xor_u64(unsigned long long v,
                                                           int off) {
  unsigned lo = (unsigned)v, hi = (unsigned)(v >> 32);
  lo = __shfl_xor(lo, off);
  hi = __shfl_xor(hi, off);
  return ((unsigned long long)hi << 32) | lo;
}

// ---------------------------------------------------------------------------
// Kernel 1: FPS. 4 blocks/batch (R0's proven structure: VGPR=32, no
// allocator fights), with two sync upgrades:
//  (a) co-XCD swizzle: blockIdx->XCD is round-robin (%8); remap so all 4
//      blocks of a batch land on ONE XCD => the sync cacheline stays in that
//      XCD's L2 and the store->spin round trip is local, not cross-chiplet.
//      (Perf heuristic only; correctness placement-independent.)
//  (b) relaxed single-u64 protocol (R1): payload d<<32 | it<<16 |
//      (0xFFFF-idx); tag-spin + parity double-buffer; no acq/rel cache ops.
// Compute trim vs R0: coords float2+float (2 LDS reads/pt, not 3 planar),
// dist[8] in registers (fits the 32-VGPR budget).
// Per round: 8-pt VALU update -> wave butterfly (u64 max == np.argmax
// first-max rule) -> redp[wave] -> barrier A -> wave0: 16-partial butterfly,
// lane0 publishes slot, lanes0-3 tag-spin on the 4 slots, 2-step butterfly,
// lane0 -> winp -> barrier B -> all read winner, coords via scalar load.
// Parity safety: round it+2's slot write happens only after this block read
// all round it+1 slots, which required every block's round-it read. 64
// blocks, 1/CU (96KB LDS) => all co-resident => spins can't deadlock.
// ---------------------------------------------------------------------------
__global__ void __launch_bounds__(NT1) k_fps(const float* __restrict__ points,
                                             float* __restrict__ out,
                                             float* __restrict__ ws) {
  __shared__ float2 xyS[SP];                 // 64 KB
  __shared__ float  zS[SP];                  // 32 KB
  __shared__ float cent[GG * 3];
  __shared__ float darr[GG];
  __shared__ int msh[1];
  __shared__ unsigned long long redp[16];
  __shared__ unsigned long long winp;

  const int gb   = blockIdx.x;
  // co-XCD mapping: xcd = gb&7; batch = xcd*2 + (gb>>5); blk = (gb>>3)&3.
  // All 4 blocks of a batch share gb%8 => same XCD under round-robin.
  const int b    = (gb & 7) * 2 + (gb >> 5);
  const int blk  = (gb >> 3) & 3;
  const int t    = threadIdx.x;
  const int wave = t >> 6, lane = t & 63;
  const float* P = points + (size_t)b * NN * 3;
  const int base = blk * SP;
  unsigned long long* slots = (unsigned long long*)(ws + WS_SYNC);

  // stage slice coords (thread-owned slots) + init reg-resident dist
#pragma unroll
  for (int j = 0; j < JP; ++j) {
    int q = t + j * NT1;
    const float* pp = P + (size_t)(base + q) * 3;
    xyS[q] = make_float2(pp[0], pp[1]);
    zS[q]  = pp[2];
  }
  float dist[JP];
#pragma unroll
  for (int j = 0; j < JP; ++j) dist[j] = INFINITY;

  float cx = P[0], cy = P[1], cz = P[2];  // centroid 0 = point 0
  if (blk == 0 && t == 0) { cent[0] = cx; cent[1] = cy; cent[2] = cz; }
  __syncthreads();

  for (int it = 1; it < GG; ++it) {
    float bd = -INFINITY; int bj = 0;
#pragma unroll
    for (int j = 0; j < JP; ++j) {
      int q = t + j * NT1;
      float2 xy = xyS[q];
      float  zz = zS[q];
      float dx = __fsub_rn(xy.x, cx);
      float dy = __fsub_rn(xy.y, cy);
      float dz = __fsub_rn(zz, cz);
      float d  = __fadd_rn(__fadd_rn(__fmul_rn(dx, dx), __fmul_rn(dy, dy)),
                           __fmul_rn(dz, dz));
      float nd = fminf(dist[j], d);
      dist[j] = nd;
      if (nd > bd) { bd = nd; bj = j; }  // ascending q + strict > => first-max
    }
    // pack: [d_bits(32) | it(16) | 0xFFFF - idx(16)]; u64 max = (max d,
    // tie min idx) = np.argmax first-max rule. idx = base+t+bj*1024 < 32768.
    unsigned long long bp =
        ((unsigned long long)__float_as_uint(bd) << 32) |
        ((unsigned)it << 16) |
        (unsigned)(0xFFFF - (base + t + (bj << 10)));
#pragma unroll
    for (int off = 1; off < 64; off <<= 1) {
      unsigned long long o = shfl_xor_u64(bp, off);
      if (o > bp) bp = o;
    }
    if (lane == 0) redp[wave] = bp;
    __syncthreads();  // barrier A
    if (wave == 0) {
      unsigned long long v = redp[lane & 15];
#pragma unroll
      for (int off = 1; off < 16; off <<= 1) {
        unsigned long long o = shfl_xor_u64(v, off);
        if (o > v) v = o;
      }
      unsigned long long* sl = slots + ((size_t)(it & 1) * 16 + b) * 4;
      if (lane == 0)
        __hip_atomic_store(&sl[blk], v, __ATOMIC_RELAXED,
                           __HIP_MEMORY_SCOPE_AGENT);
      if (lane < 4) {
        unsigned long long o;
        do {
          o = __hip_atomic_load(&sl[lane], __ATOMIC_RELAXED,
                                __HIP_MEMORY_SCOPE_AGENT);
        } while ((unsigned)((o >> 16) & 0xFFFF) != (unsigned)it);  // tag-spin
        unsigned long long o1 = shfl_xor_u64(o, 1);
        if (o1 > o) o = o1;
        unsigned long long o2 = shfl_xor_u64(o, 2);
        if (o2 > o) o = o2;
        if (lane == 0) winp = o;
      }
    }
    __syncthreads();  // barrier B
    unsigned long long w = winp;
    int sv = 0xFFFF - (int)(w & 0xFFFF);
    const float* wp = P + (size_t)sv * 3;  // wave-uniform -> broadcast load
    cx = wp[0]; cy = wp[1]; cz = wp[2];
    if (blk == 0 && t == 0) {
      cent[it * 3 + 0] = cx; cent[it * 3 + 1] = cy; cent[it * 3 + 2] = cz;
    }
  }

  if (blk != 0) return;  // epilogue on block 0 of each batch only
  __syncthreads();

  // morton step 1: m = argmin_{j>=1} cdist(c0, cj), ref expansion formula
  if (t < GG) {
    float c0x = cent[0], c0y = cent[1], c0z = cent[2];
    float cjx = cent[t * 3 + 0], cjy = cent[t * 3 + 1], cjz = cent[t * 3 + 2];
    float sa = sq3(c0x, c0y, c0z);
    float sb = sq3(cjx, cjy, cjz);
    float dt = dot3(c0x, c0y, c0z, cjx, cjy, cjz);
    float dd = __fsub_rn(__fadd_rn(sa, sb), __fmul_rn(2.0f, dt));
    darr[t] = (t == 0) ? INFINITY : dd;
  }
  __syncthreads();
  if (t == 0) {
    float vd = darr[1]; int vi = 1;
    for (int j = 2; j < GG; ++j) {
      float od = darr[j];
      if (od < vd) { vd = od; vi = j; }  // strict < => first-min
    }
    msh[0] = vi;
    float* gc = ws + WS_GC + b * 6;
    gc[0] = cent[0];          gc[1] = cent[1];          gc[2] = cent[2];
    gc[3] = cent[vi * 3 + 0]; gc[4] = cent[vi * 3 + 1]; gc[5] = cent[vi * 3 + 2];
  }
  __syncthreads();
  int m = msh[0];
  // centroid output: pos0 = c0, pos1 = cm, pos>=2 = c0 (morton degeneracy)
  if (t < GG * 3) {
    int pos = t / 3, c = t % 3;
    float v = (pos == 1) ? cent[m * 3 + c] : cent[c];
    out[(size_t)b * GG * 3 + t] = v;
  }
}

// ---------------------------------------------------------------------------
// Kernel 2 (fused topk + encA): per group (32 blocks x 1024 threads):
// top-64 extraction into LDS xl, then f1 = relu(bn1(w1@x+b1)),
// f2 = w2@f1 + b2 -> global, fg = max_k f2 -> global.
// f1s overlays the dead darr region after a barrier.
// ---------------------------------------------------------------------------
__global__ void __launch_bounds__(NT1) k_grp(
    const float* __restrict__ points, float* __restrict__ ws,
    const float* __restrict__ w1, const float* __restrict__ b1,
    const float* __restrict__ g1, const float* __restrict__ be1,
    const float* __restrict__ m1, const float* __restrict__ v1,
    const float* __restrict__ w2, const float* __restrict__ b2) {
  extern __shared__ float smem[];
  float* darr = smem;                        // [NN] (topk) / f1s overlay (encA)
  float* f1s  = smem;                        // [128*65] = 8320 <= NN
  float* redd = smem + NN;                   // [2][16]
  int*   redi = (int*)(smem + NN + 32);      // [2][16]
  float* xl   = smem + NN + 64;              // [KK*3]

  const int g = blockIdx.x;
  const int b = g >> 1, which = g & 1;
  const int t = threadIdx.x;
  const float* P = points + (size_t)b * NN * 3;
  const float* gc = ws + WS_GC + b * 6 + which * 3;
  const float cx = gc[0], cy = gc[1], cz = gc[2];
  const float sa = sq3(cx, cy, cz);

  // ---- phase 1: top-64 extraction ----
  float bd = INFINITY; int bg = 0;
#pragma unroll
  for (int j = 0; j < PPT; ++j) {
    int p = t + j * NT1;
    const float* pp = P + (size_t)p * 3;
    float px = pp[0], py = pp[1], pz = pp[2];
    float sb = sq3(px, py, pz);
    float dt = dot3(cx, cy, cz, px, py, pz);
    float d  = __fsub_rn(__fadd_rn(sa, sb), __fmul_rn(2.0f, dt));
    darr[p] = d;
    if (d < bd) { bd = d; bg = p; }  // ascending p + strict < => first-min
  }
  int my_win = 0;
  for (int r = 0; r < KK; ++r) {
    float rd = bd; int ri = bg;
#pragma unroll
    for (int off = 1; off < 64; off <<= 1) {
      float od = __shfl_xor(rd, off);
      int   oi = __shfl_xor(ri, off);
      if (od < rd || (od == rd && oi < ri)) { rd = od; ri = oi; }
    }
    const int par = (r & 1) * 16;
    if ((t & 63) == 0) { redd[par + (t >> 6)] = rd; redi[par + (t >> 6)] = ri; }
    __syncthreads();
    int l = t & 15;
    float vd = redd[par + l]; int vi = redi[par + l];
#pragma unroll
    for (int off = 1; off < 16; off <<= 1) {
      float od = __shfl_xor(vd, off);
      int   oi = __shfl_xor(vi, off);
      if (od < vd || (od == vd && oi < vi)) { vd = od; vi = oi; }
    }
    if (t == r) my_win = vi;
    if (t == (vi & (NT1 - 1))) {  // owner invalidates + rescans its 32 slots
      darr[vi] = INFINITY;
      bd = INFINITY; bg = 0;
#pragma unroll
      for (int j = 0; j < PPT; ++j) {
        int p = t + j * NT1;
        float v = darr[p];
        if (v < bd) { bd = v; bg = p; }
      }
    }
  }
  __syncthreads();  // darr dead after this point
  if (t < KK) {     // thread t holds round-t winner; local coords into LDS
    const float* pp = P + (size_t)my_win * 3;
    xl[t * 3 + 0] = __fsub_rn(pp[0], cx);
    xl[t * 3 + 1] = __fsub_rn(pp[1], cy);
    xl[t * 3 + 2] = __fsub_rn(pp[2], cz);
  }
  __syncthreads();

  // ---- phase 2: f1 = relu(bn1(w1@x + b1)) -> f1s[128][65] ----
  {
    const int o = t & 127, kh = t >> 7;  // kh in [0,8)
    float wx = w1[o * 3 + 0], wy = w1[o * 3 + 1], wz = w1[o * 3 + 2];
    float inv = g1[o] * (1.0f / sqrtf(v1[o] + 1e-5f));
    float add = be1[o] - m1[o] * inv;
    float bb = b1[o];
#pragma unroll
    for (int kk = 0; kk < 8; ++kk) {
      int k = kh * 8 + kk;
      float f = fmaf(wx, xl[k * 3 + 0],
                fmaf(wy, xl[k * 3 + 1],
                fmaf(wz, xl[k * 3 + 2], bb)));
      f = fmaf(f, inv, add);
      f1s[o * 65 + k] = fmaxf(f, 0.0f);
    }
  }
  __syncthreads();

  // ---- phase 3: f2 = w2@f1 + b2 -> global; fg = max_k -> global ----
  const int k  = t & 63;
  const int og = __builtin_amdgcn_readfirstlane(t >> 6);  // wave-uniform [0,16)
  const int o0 = og * 16;
  float acc[16];
#pragma unroll
  for (int oo = 0; oo < 16; ++oo) acc[oo] = b2[o0 + oo];
  for (int i = 0; i < 128; ++i) {
    float xv = f1s[i * 65 + k];
#pragma unroll
    for (int oo = 0; oo < 16; ++oo)
      acc[oo] = fmaf(w2[(o0 + oo) * 128 + i], xv, acc[oo]);  // uniform -> s_load
  }
  float* f2g = ws + WS_F2 + (size_t)g * 256 * 64;
  float* fgg = ws + WS_FG + g * 256;
#pragma unroll
  for (int oo = 0; oo < 16; ++oo) f2g[(o0 + oo) * 64 + k] = acc[oo];
#pragma unroll
  for (int oo = 0; oo < 16; ++oo) {
    float v = acc[oo];
#pragma unroll
    for (int off = 1; off < 64; off <<= 1) v = fmaxf(v, __shfl_xor(v, off));
    if (k == 0) fgg[o0 + oo] = v;
  }
}

// ---------------------------------------------------------------------------
// Kernel 3 (stage B): f4 = relu(bn2(w3 @ concat([fg bcast, f2]) + b3))
// grid = 32 groups x 16 o-chunks of 32 (512 blocks -> 2 blocks/CU -> 2
// waves/SIMD).
// ---------------------------------------------------------------------------
__global__ void __launch_bounds__(256) k_encB(
    float* __restrict__ ws,
    const float* __restrict__ w3, const float* __restrict__ b3,
    const float* __restrict__ g2, const float* __restrict__ be2,
    const float* __restrict__ m2, const float* __restrict__ v2) {
  __shared__ float part[32][8];
  __shared__ float sfg[32];
  const int blk = blockIdx.x;
  const int g = blk >> 4, oc = blk & 15;
  const int t = threadIdx.x;
  const int k = t & 63;
  const int og = __builtin_amdgcn_readfirstlane(t >> 6);  // [0,4)
  const int ob = oc * 32;
  const float* fgg = ws + WS_FG + g * 256;
  {  // k-independent part: sum_{i<256} w3[o][i] * fg[i]; o = t>>3, ih = t&7
    int o = t >> 3, ih = t & 7;
    float s = 0.0f;
    int i0 = ih * 32;
    for (int ii = 0; ii < 32; ++ii) {
      int i = i0 + ii;
      s = fmaf(w3[(size_t)(ob + o) * 512 + i], fgg[i], s);
    }
    part[o][ih] = s;
  }
  __syncthreads();
  if (t < 32) {
    float s = ((part[t][0] + part[t][1]) + (part[t][2] + part[t][3])) +
              ((part[t][4] + part[t][5]) + (part[t][6] + part[t][7]));
    sfg[t] = b3[ob + t] + s;
  }
  __syncthreads();
  const int o0 = ob + og * 8;
  float acc[8];
#pragma unroll
  for (int oo = 0; oo < 8; ++oo) acc[oo] = sfg[og * 8 + oo];
  const float* f2g = ws + WS_F2 + (size_t)g * 256 * 64;
#pragma unroll 4
  for (int i = 0; i < 256; ++i) {
    float xv = f2g[i * 64 + k];
#pragma unroll
    for (int oo = 0; oo < 8; ++oo)
      acc[oo] = fmaf(w3[(size_t)(o0 + oo) * 512 + 256 + i], xv, acc[oo]);
  }
  float* f4g = ws + WS_F4 + (size_t)g * 512 * 64;
#pragma unroll
  for (int oo = 0; oo < 8; ++oo) {
    int o = o0 + oo;
    float inv = g2[o] * (1.0f / sqrtf(v2[o] + 1e-5f));
    float add = be2[o] - m2[o] * inv;
    f4g[o * 64 + k] = fmaxf(fmaf(acc[oo], inv, add), 0.0f);
  }
}

// ---------------------------------------------------------------------------
// Kernel 4 (fused stage C + broadcast): token = max_k (w4 @ f4 + b4), written
// directly to all output positions (xor butterfly leaves max in ALL lanes;
// lanes scatter positions). grid = 32 x 24 chunks of 16 (768 blocks -> 2
// blocks/CU -> 2 waves/SIMD).
// ---------------------------------------------------------------------------
__global__ void __launch_bounds__(256) k_encCb(float* __restrict__ ws,
                                               const float* __restrict__ w4,
                                               const float* __restrict__ b4,
                                               float* __restrict__ out) {
  const int blk = blockIdx.x;
  const int g = blk / 24, oc = blk % 24;
  const int b = g >> 1, which = g & 1;
  const int t = threadIdx.x;
  const int k = t & 63;
  const int og = __builtin_amdgcn_readfirstlane(t >> 6);
  const int o0 = oc * 16 + og * 4;
  float acc[4];
#pragma unroll
  for (int oo = 0; oo < 4; ++oo) acc[oo] = b4[o0 + oo];
  const float* f4g = ws + WS_F4 + (size_t)g * 512 * 64;
#pragma unroll 8
  for (int i = 0; i < 512; ++i) {
    float xv = f4g[i * 64 + k];
#pragma unroll
    for (int oo = 0; oo < 4; ++oo)
      acc[oo] = fmaf(w4[(size_t)(o0 + oo) * 512 + i], xv, acc[oo]);
  }
#pragma unroll
  for (int oo = 0; oo < 4; ++oo) {
#pragma unroll
    for (int off = 1; off < 64; off <<= 1)
      acc[oo] = fmaxf(acc[oo], __shfl_xor(acc[oo], off));
  }
  // all lanes now hold the per-oo max; scatter to output positions
  float* tok = out + (size_t)BB * GG * 3;
  if (which == 1) {
    if (k == 0) {
      float* dst = tok + ((size_t)b * GG + 1) * EDD + o0;
#pragma unroll
      for (int oo = 0; oo < 4; ++oo) dst[oo] = acc[oo];
    }
  } else {
#pragma unroll
    for (int rep = 0; rep < 2; ++rep) {
      int pos = k + rep * 64;
      if (pos == 1) continue;
      float* dst = tok + ((size_t)b * GG + pos) * EDD + o0;
#pragma unroll
      for (int oo = 0; oo < 4; ++oo) dst[oo] = acc[oo];
    }
  }
}

extern "C" void kernel_launch(void* const* d_in, const int* in_sizes, int n_in,
                              void* d_out, int out_size, void* d_ws, size_t ws_size,
                              hipStream_t stream) {
  const float* points = (const float*)d_in[0];
  const float* w1  = (const float*)d_in[1];
  const float* b1  = (const float*)d_in[2];
  const float* g1  = (const float*)d_in[3];
  const float* be1 = (const float*)d_in[4];
  const float* m1  = (const float*)d_in[5];
  const float* v1  = (const float*)d_in[6];
  const float* w2  = (const float*)d_in[7];
  const float* b2  = (const float*)d_in[8];
  const float* w3  = (const float*)d_in[9];
  const float* b3  = (const float*)d_in[10];
  const float* g2  = (const float*)d_in[11];
  const float* be2 = (const float*)d_in[12];
  const float* m2  = (const float*)d_in[13];
  const float* v2  = (const float*)d_in[14];
  const float* w4  = (const float*)d_in[15];
  const float* b4  = (const float*)d_in[16];
  float* out = (float*)d_out;
  float* ws  = (float*)d_ws;

  // k_fps uses static LDS. k_grp still dynamic (>64KB opt-in).
  size_t dyn_grp = (size_t)(NN + 64 + KK * 3 + 16) * sizeof(float);
  hipFuncSetAttribute(reinterpret_cast<const void*>(k_grp),
                      hipFuncAttributeMaxDynamicSharedMemorySize, (int)dyn_grp);

  // invalidate k_fps sync slots (tag field 0xAAAA != any round); graph-safe.
  hipMemsetAsync(ws + WS_SYNC, 0xAA, (size_t)2 * 16 * 4 * 8, stream);

  hipLaunchKernelGGL(k_fps, dim3(BB * SB), dim3(NT1), 0, stream,
                     points, out, ws);
  hipLaunchKernelGGL(k_grp, dim3(32), dim3(NT1), dyn_grp, stream,
                     points, ws, w1, b1, g1, be1, m1, v1, w2, b2);
  hipLaunchKernelGGL(k_encB, dim3(512), dim3(256), 0, stream,
                     ws, w3, b3, g2, be2, m2, v2);
  hipLaunchKernelGGL(k_encCb, dim3(768), dim3(256), 0, stream, ws, w4, b4, out);
}

// Round 9
// 503.696 us; speedup vs baseline: 1.4347x; 1.1237x over previous
//
#include <hip/hip_runtime.h>
#include <math.h>

#define BB   16
#define NN   32768
#define GG   128
#define KK   64
#define EDD  384
#define NT1  1024
#define PPT  32   // NN / NT1 (k_grp phases)
#define SB   4    // k_fps blocks per batch
#define SP   (NN / SB)   // 8192 points per k_fps block
#define JP   (SP / NT1)  // 8 points/thread

// ---- workspace layout (float offsets) ----
#define WS_GC     0          // [16][2][3]      = 96     (c0, cm per batch)
#define WS_F2     6240       // [32][256][64]   = 524288
#define WS_FG     530528     // [32][256]       = 8192
#define WS_F4     538720     // [32][512][64]   = 1048576
#define WS_SYNC   1587296    // u64 [2 parity][16 batch][4 blk] = 1 KB

// ---- k_grp LDS layout (float offsets past dkey[NN]) ----
#define GOFF_WSUM  (NN)        // uint [2][16] parity-buffered wave sums
#define GOFF_CNT   (NN + 32)   // int [8]: [0]=sel_cnt [1]=eq_cnt
#define GOFF_SEL   (NN + 40)   // int [64]
#define GOFF_EQB   (NN + 104)  // int [512]
#define GOFF_XL    (NN + 616)  // float [KK*3]
#define GRP_LDS_FLOATS (NN + 808)

__device__ __forceinline__ float sq3(float a, float b, float c) {
  // matches np: ((a*a + b*b) + c*c), no FMA contraction
  return __fadd_rn(__fadd_rn(__fmul_rn(a, a), __fmul_rn(b, b)), __fmul_rn(c, c));
}
__device__ __forceinline__ float dot3(float ax, float ay, float az,
                                      float bx, float by, float bz) {
  return __fadd_rn(__fadd_rn(__fmul_rn(ax, bx), __fmul_rn(ay, by)), __fmul_rn(az, bz));
}
__device__ __forceinline__ unsigned long long shfl_xor_u64(unsigned long long v,
                                                           int off) {
  unsigned lo = (unsigned)v, hi = (unsigned)(v >> 32);
  lo = __shfl_xor(lo, off);
  hi = __shfl_xor(hi, off);
  return ((unsigned long long)hi << 32) | lo;
}

// ---------------------------------------------------------------------------
// Kernel 1: FPS (UNCHANGED from R8: 289 us measured, VGPR=52).
// 4 blocks/batch, co-XCD swizzle, relaxed single-u64 tag-spin sync,
// float2+float LDS coords, register dist[8].
// ---------------------------------------------------------------------------
__global__ void __launch_bounds__(NT1) k_fps(const float* __restrict__ points,
                                             float* __restrict__ out,
                                             float* __restrict__ ws) {
  __shared__ float2 xyS[SP];                 // 64 KB
  __shared__ float  zS[SP];                  // 32 KB
  __shared__ float cent[GG * 3];
  __shared__ float darr[GG];
  __shared__ int msh[1];
  __shared__ unsigned long long redp[16];
  __shared__ unsigned long long winp;

  const int gb   = blockIdx.x;
  // co-XCD mapping: all 4 blocks of a batch share gb%8 => same XCD.
  const int b    = (gb & 7) * 2 + (gb >> 5);
  const int blk  = (gb >> 3) & 3;
  const int t    = threadIdx.x;
  const int wave = t >> 6, lane = t & 63;
  const float* P = points + (size_t)b * NN * 3;
  const int base = blk * SP;
  unsigned long long* slots = (unsigned long long*)(ws + WS_SYNC);

#pragma unroll
  for (int j = 0; j < JP; ++j) {
    int q = t + j * NT1;
    const float* pp = P + (size_t)(base + q) * 3;
    xyS[q] = make_float2(pp[0], pp[1]);
    zS[q]  = pp[2];
  }
  float dist[JP];
#pragma unroll
  for (int j = 0; j < JP; ++j) dist[j] = INFINITY;

  float cx = P[0], cy = P[1], cz = P[2];  // centroid 0 = point 0
  if (blk == 0 && t == 0) { cent[0] = cx; cent[1] = cy; cent[2] = cz; }
  __syncthreads();

  for (int it = 1; it < GG; ++it) {
    float bd = -INFINITY; int bj = 0;
#pragma unroll
    for (int j = 0; j < JP; ++j) {
      int q = t + j * NT1;
      float2 xy = xyS[q];
      float  zz = zS[q];
      float dx = __fsub_rn(xy.x, cx);
      float dy = __fsub_rn(xy.y, cy);
      float dz = __fsub_rn(zz, cz);
      float d  = __fadd_rn(__fadd_rn(__fmul_rn(dx, dx), __fmul_rn(dy, dy)),
                           __fmul_rn(dz, dz));
      float nd = fminf(dist[j], d);
      dist[j] = nd;
      if (nd > bd) { bd = nd; bj = j; }  // ascending q + strict > => first-max
    }
    unsigned long long bp =
        ((unsigned long long)__float_as_uint(bd) << 32) |
        ((unsigned)it << 16) |
        (unsigned)(0xFFFF - (base + t + (bj << 10)));
#pragma unroll
    for (int off = 1; off < 64; off <<= 1) {
      unsigned long long o = shfl_xor_u64(bp, off);
      if (o > bp) bp = o;
    }
    if (lane == 0) redp[wave] = bp;
    __syncthreads();  // barrier A
    if (wave == 0) {
      unsigned long long v = redp[lane & 15];
#pragma unroll
      for (int off = 1; off < 16; off <<= 1) {
        unsigned long long o = shfl_xor_u64(v, off);
        if (o > v) v = o;
      }
      unsigned long long* sl = slots + ((size_t)(it & 1) * 16 + b) * 4;
      if (lane == 0)
        __hip_atomic_store(&sl[blk], v, __ATOMIC_RELAXED,
                           __HIP_MEMORY_SCOPE_AGENT);
      if (lane < 4) {
        unsigned long long o;
        do {
          o = __hip_atomic_load(&sl[lane], __ATOMIC_RELAXED,
                                __HIP_MEMORY_SCOPE_AGENT);
        } while ((unsigned)((o >> 16) & 0xFFFF) != (unsigned)it);  // tag-spin
        unsigned long long o1 = shfl_xor_u64(o, 1);
        if (o1 > o) o = o1;
        unsigned long long o2 = shfl_xor_u64(o, 2);
        if (o2 > o) o = o2;
        if (lane == 0) winp = o;
      }
    }
    __syncthreads();  // barrier B
    unsigned long long w = winp;
    int sv = 0xFFFF - (int)(w & 0xFFFF);
    const float* wp = P + (size_t)sv * 3;  // wave-uniform -> broadcast load
    cx = wp[0]; cy = wp[1]; cz = wp[2];
    if (blk == 0 && t == 0) {
      cent[it * 3 + 0] = cx; cent[it * 3 + 1] = cy; cent[it * 3 + 2] = cz;
    }
  }

  if (blk != 0) return;  // epilogue on block 0 of each batch only
  __syncthreads();

  if (t < GG) {
    float c0x = cent[0], c0y = cent[1], c0z = cent[2];
    float cjx = cent[t * 3 + 0], cjy = cent[t * 3 + 1], cjz = cent[t * 3 + 2];
    float sa = sq3(c0x, c0y, c0z);
    float sb = sq3(cjx, cjy, cjz);
    float dt = dot3(c0x, c0y, c0z, cjx, cjy, cjz);
    float dd = __fsub_rn(__fadd_rn(sa, sb), __fmul_rn(2.0f, dt));
    darr[t] = (t == 0) ? INFINITY : dd;
  }
  __syncthreads();
  if (t == 0) {
    float vd = darr[1]; int vi = 1;
    for (int j = 2; j < GG; ++j) {
      float od = darr[j];
      if (od < vd) { vd = od; vi = j; }  // strict < => first-min
    }
    msh[0] = vi;
    float* gc = ws + WS_GC + b * 6;
    gc[0] = cent[0];          gc[1] = cent[1];          gc[2] = cent[2];
    gc[3] = cent[vi * 3 + 0]; gc[4] = cent[vi * 3 + 1]; gc[5] = cent[vi * 3 + 2];
  }
  __syncthreads();
  int m = msh[0];
  if (t < GG * 3) {
    int pos = t / 3, c = t % 3;
    float v = (pos == 1) ? cent[m * 3 + c] : cent[c];
    out[(size_t)b * GG * 3 + t] = v;
  }
}

// ---------------------------------------------------------------------------
// Kernel 2 (fused topk + encA), R9 rewrite of the selection phase.
// OLD: 64 serial extraction rounds (butterfly + barrier + owner-rescan each)
// ~1.5-3 us/round. NEW: exact binary search on the 32-bit monotone key
// transform of d (32 counting rounds, ONE parity-buffered barrier each),
// then one atomic-append collection pass (key < K64) + index-ordered tie
// resolution for key == K64. Matches lax.top_k(-d,K)'s SET exactly
// ((d, idx) lexicographic; equal d -> lower index). The encoder is
// permutation-invariant in k (all ops per-k elementwise or max over k), so
// set equality => bitwise-identical output; within-sel order may vary
// run-to-run without affecting results.
// ---------------------------------------------------------------------------
__global__ void __launch_bounds__(NT1) k_grp(
    const float* __restrict__ points, float* __restrict__ ws,
    const float* __restrict__ w1, const float* __restrict__ b1,
    const float* __restrict__ g1, const float* __restrict__ be1,
    const float* __restrict__ m1, const float* __restrict__ v1,
    const float* __restrict__ w2, const float* __restrict__ b2) {
  extern __shared__ float smem[];
  unsigned* dkey = (unsigned*)smem;          // [NN] keys; f1s overlays later
  float* f1s  = smem;                        // [128*65] = 8320 <= NN
  unsigned* wsum = (unsigned*)(smem + GOFF_WSUM);  // [2][16]
  int*   cnts = (int*)(smem + GOFF_CNT);     // [0]=sel_cnt [1]=eq_cnt
  int*   sel  = (int*)(smem + GOFF_SEL);     // [64]
  int*   eqb  = (int*)(smem + GOFF_EQB);     // [512]
  float* xl   = smem + GOFF_XL;              // [KK*3]

  const int g = blockIdx.x;
  const int b = g >> 1, which = g & 1;
  const int t = threadIdx.x;
  const int wave = t >> 6, lane = t & 63;
  const float* P = points + (size_t)b * NN * 3;
  const float* gc = ws + WS_GC + b * 6 + which * 3;
  const float cx = gc[0], cy = gc[1], cz = gc[2];
  const float sa = sq3(cx, cy, cz);

  // ---- phase 1: distances -> monotone uint keys in LDS ----
#pragma unroll
  for (int j = 0; j < PPT; ++j) {
    int p = t + j * NT1;
    const float* pp = P + (size_t)p * 3;
    float px = pp[0], py = pp[1], pz = pp[2];
    float sb = sq3(px, py, pz);
    float dt = dot3(cx, cy, cz, px, py, pz);
    float d  = __fsub_rn(__fadd_rn(sa, sb), __fmul_rn(2.0f, dt));
    unsigned u = __float_as_uint(d);
    // standard float->uint order-preserving transform (handles negatives)
    dkey[p] = u ^ ((u & 0x80000000u) ? 0xFFFFFFFFu : 0x80000000u);
  }
  if (t < 2) cnts[t] = 0;
  __syncthreads();

  // ---- phase 2: binary search for K = min key with count(<=K) >= 64 ----
  unsigned klo = 0u, khi = 0xFFFFFFFFu;
  int par = 0;
  while (klo < khi) {  // uniform across block: 32 iterations
    unsigned mid = klo + ((khi - klo) >> 1);
    int c = 0;
#pragma unroll
    for (int j = 0; j < PPT; ++j) c += (dkey[t + j * NT1] <= mid) ? 1 : 0;
#pragma unroll
    for (int off = 1; off < 64; off <<= 1) c += __shfl_xor(c, off);
    if (lane == 0) wsum[par * 16 + wave] = (unsigned)c;
    __syncthreads();  // one barrier/iter; parity buffer kills WAR race
    int tot = 0;
#pragma unroll
    for (int w = 0; w < 16; ++w) tot += (int)wsum[par * 16 + w];
    if (tot >= KK) khi = mid; else klo = mid + 1;
    par ^= 1;
  }
  const unsigned K64 = klo;

  // count(< K64) — uniform C_lt
  {
    int c = 0;
#pragma unroll
    for (int j = 0; j < PPT; ++j) c += (dkey[t + j * NT1] < K64) ? 1 : 0;
#pragma unroll
    for (int off = 1; off < 64; off <<= 1) c += __shfl_xor(c, off);
    if (lane == 0) wsum[par * 16 + wave] = (unsigned)c;
    __syncthreads();
  }
  int C_lt = 0;
#pragma unroll
  for (int w = 0; w < 16; ++w) C_lt += (int)wsum[par * 16 + w];

  // ---- phase 3: collection (set-exact; order within sel arbitrary) ----
#pragma unroll
  for (int j = 0; j < PPT; ++j) {
    int p = t + j * NT1;
    unsigned kk = dkey[p];
    if (kk < K64) {
      int pos = atomicAdd(&cnts[0], 1);
      sel[pos] = p;
    } else if (kk == K64) {
      int pos = atomicAdd(&cnts[1], 1);
      if (pos < 512) eqb[pos] = p;
    }
  }
  __syncthreads();

  // ties: take (KK - C_lt) smallest INDICES among key==K64 (top_k rule)
  if (wave == 0) {
    int M = cnts[1]; if (M > 512) M = 512;
    int R = KK - C_lt;  // >=1 by minimality of K64
    int e[8];
#pragma unroll
    for (int q = 0; q < 8; ++q) {
      int ix = lane + q * 64;
      e[q] = (ix < M) ? eqb[ix] : 0x7FFFFFFF;
    }
    for (int r = 0; r < R; ++r) {
      int gm = e[0];
#pragma unroll
      for (int q = 1; q < 8; ++q) gm = min(gm, e[q]);
#pragma unroll
      for (int off = 1; off < 64; off <<= 1) gm = min(gm, __shfl_xor(gm, off));
      if (lane == 0) sel[C_lt + r] = gm;
#pragma unroll
      for (int q = 0; q < 8; ++q) if (e[q] == gm) e[q] = 0x7FFFFFFF;
    }
  }
  __syncthreads();

  if (t < KK) {  // local coords of the 64 selected into LDS
    int p = sel[t];
    const float* pp = P + (size_t)p * 3;
    xl[t * 3 + 0] = __fsub_rn(pp[0], cx);
    xl[t * 3 + 1] = __fsub_rn(pp[1], cy);
    xl[t * 3 + 2] = __fsub_rn(pp[2], cz);
  }
  __syncthreads();  // dkey dead after this point; f1s overlays it

  // ---- phase 4: f1 = relu(bn1(w1@x + b1)) -> f1s[128][65] ----
  {
    const int o = t & 127, kh = t >> 7;  // kh in [0,8)
    float wx = w1[o * 3 + 0], wy = w1[o * 3 + 1], wz = w1[o * 3 + 2];
    float inv = g1[o] * (1.0f / sqrtf(v1[o] + 1e-5f));
    float add = be1[o] - m1[o] * inv;
    float bb = b1[o];
#pragma unroll
    for (int kk = 0; kk < 8; ++kk) {
      int k = kh * 8 + kk;
      float f = fmaf(wx, xl[k * 3 + 0],
                fmaf(wy, xl[k * 3 + 1],
                fmaf(wz, xl[k * 3 + 2], bb)));
      f = fmaf(f, inv, add);
      f1s[o * 65 + k] = fmaxf(f, 0.0f);
    }
  }
  __syncthreads();

  // ---- phase 5: f2 = w2@f1 + b2 -> global; fg = max_k -> global ----
  const int k  = t & 63;
  const int og = __builtin_amdgcn_readfirstlane(t >> 6);  // wave-uniform [0,16)
  const int o0 = og * 16;
  float acc[16];
#pragma unroll
  for (int oo = 0; oo < 16; ++oo) acc[oo] = b2[o0 + oo];
  for (int i = 0; i < 128; ++i) {
    float xv = f1s[i * 65 + k];
#pragma unroll
    for (int oo = 0; oo < 16; ++oo)
      acc[oo] = fmaf(w2[(o0 + oo) * 128 + i], xv, acc[oo]);  // uniform -> s_load
  }
  float* f2g = ws + WS_F2 + (size_t)g * 256 * 64;
  float* fgg = ws + WS_FG + g * 256;
#pragma unroll
  for (int oo = 0; oo < 16; ++oo) f2g[(o0 + oo) * 64 + k] = acc[oo];
#pragma unroll
  for (int oo = 0; oo < 16; ++oo) {
    float v = acc[oo];
#pragma unroll
    for (int off = 1; off < 64; off <<= 1) v = fmaxf(v, __shfl_xor(v, off));
    if (k == 0) fgg[o0 + oo] = v;
  }
}

// ---------------------------------------------------------------------------
// Kernel 3 (stage B): f4 = relu(bn2(w3 @ concat([fg bcast, f2]) + b3))
// grid = 32 groups x 16 o-chunks of 32. (unchanged)
// ---------------------------------------------------------------------------
__global__ void __launch_bounds__(256) k_encB(
    float* __restrict__ ws,
    const float* __restrict__ w3, const float* __restrict__ b3,
    const float* __restrict__ g2, const float* __restrict__ be2,
    const float* __restrict__ m2, const float* __restrict__ v2) {
  __shared__ float part[32][8];
  __shared__ float sfg[32];
  const int blk = blockIdx.x;
  const int g = blk >> 4, oc = blk & 15;
  const int t = threadIdx.x;
  const int k = t & 63;
  const int og = __builtin_amdgcn_readfirstlane(t >> 6);  // [0,4)
  const int ob = oc * 32;
  const float* fgg = ws + WS_FG + g * 256;
  {
    int o = t >> 3, ih = t & 7;
    float s = 0.0f;
    int i0 = ih * 32;
    for (int ii = 0; ii < 32; ++ii) {
      int i = i0 + ii;
      s = fmaf(w3[(size_t)(ob + o) * 512 + i], fgg[i], s);
    }
    part[o][ih] = s;
  }
  __syncthreads();
  if (t < 32) {
    float s = ((part[t][0] + part[t][1]) + (part[t][2] + part[t][3])) +
              ((part[t][4] + part[t][5]) + (part[t][6] + part[t][7]));
    sfg[t] = b3[ob + t] + s;
  }
  __syncthreads();
  const int o0 = ob + og * 8;
  float acc[8];
#pragma unroll
  for (int oo = 0; oo < 8; ++oo) acc[oo] = sfg[og * 8 + oo];
  const float* f2g = ws + WS_F2 + (size_t)g * 256 * 64;
#pragma unroll 4
  for (int i = 0; i < 256; ++i) {
    float xv = f2g[i * 64 + k];
#pragma unroll
    for (int oo = 0; oo < 8; ++oo)
      acc[oo] = fmaf(w3[(size_t)(o0 + oo) * 512 + 256 + i], xv, acc[oo]);
  }
  float* f4g = ws + WS_F4 + (size_t)g * 512 * 64;
#pragma unroll
  for (int oo = 0; oo < 8; ++oo) {
    int o = o0 + oo;
    float inv = g2[o] * (1.0f / sqrtf(v2[o] + 1e-5f));
    float add = be2[o] - m2[o] * inv;
    f4g[o * 64 + k] = fmaxf(fmaf(acc[oo], inv, add), 0.0f);
  }
}

// ---------------------------------------------------------------------------
// Kernel 4 (fused stage C + broadcast): token = max_k (w4 @ f4 + b4).
// grid = 32 x 24 chunks of 16. (unchanged)
// ---------------------------------------------------------------------------
__global__ void __launch_bounds__(256) k_encCb(float* __restrict__ ws,
                                               const float* __restrict__ w4,
                                               const float* __restrict__ b4,
                                               float* __restrict__ out) {
  const int blk = blockIdx.x;
  const int g = blk / 24, oc = blk % 24;
  const int b = g >> 1, which = g & 1;
  const int t = threadIdx.x;
  const int k = t & 63;
  const int og = __builtin_amdgcn_readfirstlane(t >> 6);
  const int o0 = oc * 16 + og * 4;
  float acc[4];
#pragma unroll
  for (int oo = 0; oo < 4; ++oo) acc[oo] = b4[o0 + oo];
  const float* f4g = ws + WS_F4 + (size_t)g * 512 * 64;
#pragma unroll 8
  for (int i = 0; i < 512; ++i) {
    float xv = f4g[i * 64 + k];
#pragma unroll
    for (int oo = 0; oo < 4; ++oo)
      acc[oo] = fmaf(w4[(size_t)(o0 + oo) * 512 + i], xv, acc[oo]);
  }
#pragma unroll
  for (int oo = 0; oo < 4; ++oo) {
#pragma unroll
    for (int off = 1; off < 64; off <<= 1)
      acc[oo] = fmaxf(acc[oo], __shfl_xor(acc[oo], off));
  }
  float* tok = out + (size_t)BB * GG * 3;
  if (which == 1) {
    if (k == 0) {
      float* dst = tok + ((size_t)b * GG + 1) * EDD + o0;
#pragma unroll
      for (int oo = 0; oo < 4; ++oo) dst[oo] = acc[oo];
    }
  } else {
#pragma unroll
    for (int rep = 0; rep < 2; ++rep) {
      int pos = k + rep * 64;
      if (pos == 1) continue;
      float* dst = tok + ((size_t)b * GG + pos) * EDD + o0;
#pragma unroll
      for (int oo = 0; oo < 4; ++oo) dst[oo] = acc[oo];
    }
  }
}

extern "C" void kernel_launch(void* const* d_in, const int* in_sizes, int n_in,
                              void* d_out, int out_size, void* d_ws, size_t ws_size,
                              hipStream_t stream) {
  const float* points = (const float*)d_in[0];
  const float* w1  = (const float*)d_in[1];
  const float* b1  = (const float*)d_in[2];
  const float* g1  = (const float*)d_in[3];
  const float* be1 = (const float*)d_in[4];
  const float* m1  = (const float*)d_in[5];
  const float* v1  = (const float*)d_in[6];
  const float* w2  = (const float*)d_in[7];
  const float* b2  = (const float*)d_in[8];
  const float* w3  = (const float*)d_in[9];
  const float* b3  = (const float*)d_in[10];
  const float* g2  = (const float*)d_in[11];
  const float* be2 = (const float*)d_in[12];
  const float* m2  = (const float*)d_in[13];
  const float* v2  = (const float*)d_in[14];
  const float* w4  = (const float*)d_in[15];
  const float* b4  = (const float*)d_in[16];
  float* out = (float*)d_out;
  float* ws  = (float*)d_ws;

  // k_fps uses static LDS. k_grp dynamic (>64KB opt-in).
  size_t dyn_grp = (size_t)GRP_LDS_FLOATS * sizeof(float);  // ~131 KB
  hipFuncSetAttribute(reinterpret_cast<const void*>(k_grp),
                      hipFuncAttributeMaxDynamicSharedMemorySize, (int)dyn_grp);

  // invalidate k_fps sync slots (tag field 0xAAAA != any round); graph-safe.
  hipMemsetAsync(ws + WS_SYNC, 0xAA, (size_t)2 * 16 * 4 * 8, stream);

  hipLaunchKernelGGL(k_fps, dim3(BB * SB), dim3(NT1), 0, stream,
                     points, out, ws);
  hipLaunchKernelGGL(k_grp, dim3(32), dim3(NT1), dyn_grp, stream,
                     points, ws, w1, b1, g1, be1, m1, v1, w2, b2);
  hipLaunchKernelGGL(k_encB, dim3(512), dim3(256), 0, stream,
                     ws, w3, b3, g2, be2, m2, v2);
  hipLaunchKernelGGL(k_encCb, dim3(768), dim3(256), 0, stream, ws, w4, b4, out);
}